// Round 9
// baseline (110.978 us; speedup 1.0000x reference)
//
#include <hip/hip_runtime.h>
#include <math.h>

#define BB 2048
#define T  200
#define H  64
#define H1 80
#define H2 40
#define BT (BB * T)          // 409600

typedef __attribute__((ext_vector_type(8))) short short8;
typedef __attribute__((ext_vector_type(4))) short s4v;
typedef __attribute__((ext_vector_type(4))) float floatx4;

// ws layout:
//   ushort: W1P [80][128] | W2B [3][5][64][4]
//   float : QH [2048][80] | SC [2048][256]
//   ushort: KB bf16 keys [BT][64]
#define WS_W1P_US 0
#define WS_W2B_US (H1 * 128)                  // 10240
#define WS_US_END (WS_W2B_US + 3840)          // 14080
#define WS_QH_F   (WS_US_END / 2)             // 7040
#define WS_SC_F   (WS_QH_F + BB * H1)         // 170880
#define WS_F_END  (WS_SC_F + BB * 256)        // 695168
#define WS_KB_US  (WS_F_END * 2)              // 1390336

__device__ __forceinline__ unsigned short f2b(float x) {
    union { float f; unsigned u; } v; v.f = x;
    unsigned r = v.u + 0x7FFF + ((v.u >> 16) & 1);   // RNE (finite inputs only)
    return (unsigned short)(r >> 16);
}
__device__ __forceinline__ float b2f(unsigned short u) {
    union { unsigned u; float f; } v; v.u = ((unsigned)u) << 16;
    return v.f;
}

__device__ __forceinline__ floatx4 mfma16(s4v a, s4v b, floatx4 c) {
#if __has_builtin(__builtin_amdgcn_mfma_f32_16x16x16bf16_1k)
    return __builtin_amdgcn_mfma_f32_16x16x16bf16_1k(a, b, c, 0, 0, 0);
#else
    floatx4 d;
    asm volatile("s_nop 1\n\t"
                 "v_mfma_f32_16x16x16_bf16 %0, %1, %2, %3\n\t"
                 "s_nop 7\n\ts_nop 4"
                 : "=v"(d) : "v"(a), "v"(b), "v"(c));
    return d;
#endif
}

// ---------------- prep: W1' bf16, W2 B-frag table, qh[b][f] ----------------
__global__ __launch_bounds__(256)
void prep_kernel(const float* __restrict__ W1, const float* __restrict__ W2,
                 const float* __restrict__ b1, const float* __restrict__ query,
                 float* __restrict__ ws) {
    int gid = blockIdx.x * 256 + threadIdx.x;      // 0 .. 163839
    unsigned short* wsu = (unsigned short*)ws;
    if (gid < H1 * 128) {                          // W' = [Wk - Wm ; Wp]  [f][k]
        int f = gid >> 7, k = gid & 127;
        float v = (k < H) ? W1[(64 + k) * H1 + f] - W1[(128 + k) * H1 + f]
                          : W1[(192 + (k - 64)) * H1 + f];
        wsu[WS_W1P_US + gid] = f2b(v);
    }
    if (gid < 3840) {                              // W2 B-frags for 16x16x16
        int j = gid & 3, lane = (gid >> 2) & 63, tk = gid >> 8;   // tk 0..14
        int nt = tk / 5, kk = tk - nt * 5;
        int f = kk * 16 + (lane >> 4) * 4 + j;     // k index of frag elem
        int g = nt * 16 + (lane & 15);             // n index
        float v = (g < H2) ? W2[f * H2 + g] : 0.f;
        wsu[WS_W2B_US + gid] = f2b(v);
    }
    // qh[b][f] = b1[f] + q[b] @ (Wq + Wm)
    int b = gid / H1, f = gid - b * H1;
    const float* q = query + (size_t)b * H;
    float acc = b1[f];
    #pragma unroll 8
    for (int h = 0; h < H; ++h)
        acc += q[h] * (W1[h * H1 + f] + W1[(128 + h) * H1 + f]);
    ws[WS_QH_F + gid] = acc;
}

// ------- scores: barrier-free, LDS-free; 64 bt-rows per 256-thr block -------
__global__ __launch_bounds__(256, 4)
void score_kernel(const float* __restrict__ query,
                  const float* __restrict__ keys,
                  const float* __restrict__ b2,
                  const float* __restrict__ Wfc,
                  const float* __restrict__ bfc,
                  float* __restrict__ ws)
{
    const int tid = threadIdx.x;
    const int wv = tid >> 6, ln = tid & 63;
    const int lrow = ln & 15, g16 = ln >> 4, lk8 = g16 * 8;
    const int bt0w = blockIdx.x * 64 + wv * 16;    // wave's 16 t-rows
    const int t_lane = bt0w + lrow;                // this lane's key row
    const int b_lane = t_lane / T;
    unsigned short* wsu = (unsigned short*)ws;

    // ---- direct global->reg key/q fragments (coalesced: 4 lanes per 128B row)
    const float4* krow4 = reinterpret_cast<const float4*>(keys + (size_t)t_lane * H);
    const float4* qrow4 = reinterpret_cast<const float4*>(query + (size_t)b_lane * H);
    short8 af[2], af23[2];
    #pragma unroll
    for (int ks = 0; ks < 2; ++ks) {
        float4 k0 = krow4[ks * 8 + g16 * 2];
        float4 k1 = krow4[ks * 8 + g16 * 2 + 1];
        float4 q0 = qrow4[ks * 8 + g16 * 2];
        float4 q1 = qrow4[ks * 8 + g16 * 2 + 1];
        af[ks][0] = (short)f2b(k0.x);  af23[ks][0] = (short)f2b(k0.x * q0.x);
        af[ks][1] = (short)f2b(k0.y);  af23[ks][1] = (short)f2b(k0.y * q0.y);
        af[ks][2] = (short)f2b(k0.z);  af23[ks][2] = (short)f2b(k0.z * q0.z);
        af[ks][3] = (short)f2b(k0.w);  af23[ks][3] = (short)f2b(k0.w * q0.w);
        af[ks][4] = (short)f2b(k1.x);  af23[ks][4] = (short)f2b(k1.x * q1.x);
        af[ks][5] = (short)f2b(k1.y);  af23[ks][5] = (short)f2b(k1.y * q1.y);
        af[ks][6] = (short)f2b(k1.z);  af23[ks][6] = (short)f2b(k1.z * q1.z);
        af[ks][7] = (short)f2b(k1.w);  af23[ks][7] = (short)f2b(k1.w * q1.w);
    }
    // spill bf16 keys for attn_out
    #pragma unroll
    for (int ks = 0; ks < 2; ++ks)
        *reinterpret_cast<short8*>(
            &wsu[WS_KB_US + (size_t)t_lane * 64 + ks * 32 + lk8]) = af[ks];

    // ---- stage 1 (swapped operands): D[f][t] -> lane holds hid[t_lane][4 f's]
    const unsigned short* w1p = wsu + WS_W1P_US;
    const float* qhb = ws + WS_QH_F + b_lane * H1;
    unsigned pk[5][2];
    #pragma unroll
    for (int mt = 0; mt < 5; ++mt) {
        const unsigned short* wr = w1p + (mt * 16 + lrow) * 128;   // A row = f
        short8 bf0 = *reinterpret_cast<const short8*>(wr + lk8);
        short8 bf1 = *reinterpret_cast<const short8*>(wr + 32 + lk8);
        short8 bf2 = *reinterpret_cast<const short8*>(wr + 64 + lk8);
        short8 bf3 = *reinterpret_cast<const short8*>(wr + 96 + lk8);
        floatx4 acc = {0.f, 0.f, 0.f, 0.f};
        acc = __builtin_amdgcn_mfma_f32_16x16x32_bf16(bf0, af[0],   acc, 0, 0, 0);
        acc = __builtin_amdgcn_mfma_f32_16x16x32_bf16(bf1, af[1],   acc, 0, 0, 0);
        acc = __builtin_amdgcn_mfma_f32_16x16x32_bf16(bf2, af23[0], acc, 0, 0, 0);
        acc = __builtin_amdgcn_mfma_f32_16x16x32_bf16(bf3, af23[1], acc, 0, 0, 0);
        int fb = mt * 16 + g16 * 4;                 // D row = f = mt*16+g16*4+r
        float r0 = fmaxf(acc[0] + qhb[fb + 0], 0.f);
        float r1 = fmaxf(acc[1] + qhb[fb + 1], 0.f);
        float r2 = fmaxf(acc[2] + qhb[fb + 2], 0.f);
        float r3 = fmaxf(acc[3] + qhb[fb + 3], 0.f);
        pk[mt][0] = (unsigned)f2b(r0) | ((unsigned)f2b(r1) << 16);
        pk[mt][1] = (unsigned)f2b(r2) | ((unsigned)f2b(r3) << 16);
    }

    // ---- stage 2: 16x16x16 MFMAs; pk[kk] IS the A-frag for k-step kk ----
    const s4v* w2b = reinterpret_cast<const s4v*>(wsu + WS_W2B_US);
    float vsum[4] = {0.f, 0.f, 0.f, 0.f};
    #pragma unroll
    for (int nt = 0; nt < 3; ++nt) {
        int g = nt * 16 + lrow;
        float wf = (g < H2) ? Wfc[g] : 0.f;
        float bb = (g < H2) ? b2[g] : 0.f;
        floatx4 acc = {0.f, 0.f, 0.f, 0.f};
        #pragma unroll
        for (int kk = 0; kk < 5; ++kk) {
            union { unsigned u[2]; s4v s; } ua;
            ua.u[0] = pk[kk][0]; ua.u[1] = pk[kk][1];
            s4v b4 = w2b[(nt * 5 + kk) * 64 + ln];
            acc = mfma16(ua.s, b4, acc);
        }
        #pragma unroll
        for (int r = 0; r < 4; ++r)
            vsum[r] += fmaxf(acc[r] + bb, 0.f) * wf;
    }
    #pragma unroll
    for (int r = 0; r < 4; ++r) {
        vsum[r] += __shfl_xor(vsum[r], 1);
        vsum[r] += __shfl_xor(vsum[r], 2);
        vsum[r] += __shfl_xor(vsum[r], 4);
        vsum[r] += __shfl_xor(vsum[r], 8);
    }
    if (lrow == 0) {
        float bfc0 = bfc[0];
        #pragma unroll
        for (int r = 0; r < 4; ++r) {
            int t = bt0w + g16 * 4 + r;            // D2 row = t-local
            int bR = t / T, tR = t - bR * T;
            ws[WS_SC_F + bR * 256 + tR] = (vsum[r] + bfc0) * 0.125f;
        }
    }
}

// ---------------- softmax + weighted key sum (bf16 keys from ws) ----------------
__global__ __launch_bounds__(256)
void attn_out_kernel(const int* __restrict__ keys_length,
                     const float* __restrict__ ws,
                     float* __restrict__ out)
{
    __shared__ float sS[256];
    __shared__ float sRed[8];
    __shared__ float sOutp[4][64];
    const int b = blockIdx.x;
    const int tid = threadIdx.x;
    const int wv = tid >> 6, ln = tid & 63;
    const int len = keys_length[b];

    float s = -INFINITY;
    if (tid < len) s = ws[WS_SC_F + b * 256 + tid];
    float m = s;
    #pragma unroll
    for (int off = 32; off > 0; off >>= 1) m = fmaxf(m, __shfl_xor(m, off));
    if (ln == 0) sRed[wv] = m;
    __syncthreads();
    float mx = fmaxf(fmaxf(sRed[0], sRed[1]), fmaxf(sRed[2], sRed[3]));
    float e = (tid < len) ? __expf(s - mx) : 0.f;
    sS[tid] = e;
    float sum = e;
    #pragma unroll
    for (int off = 32; off > 0; off >>= 1) sum += __shfl_xor(sum, off);
    if (ln == 0) sRed[4 + wv] = sum;
    __syncthreads();
    float denom = (sRed[4] + sRed[5]) + (sRed[6] + sRed[7]);
    float inv = 1.f / denom;

    const unsigned short* kbu = (const unsigned short*)ws + WS_KB_US + (size_t)b * T * 64;
    const int c = tid & 7;          // 8-bf16 chunk (h = c*8 .. c*8+7)
    const int rg = tid >> 3;        // 0..31 row group
    float acc[8];
    #pragma unroll
    for (int j = 0; j < 8; ++j) acc[j] = 0.f;
    #pragma unroll
    for (int k = 0; k < 7; ++k) {
        int t = rg + (k << 5);
        if (t < T) {
            float w = sS[t];
            uint4 v = *reinterpret_cast<const uint4*>(&kbu[t * 64 + c * 8]);
            acc[0] += w * b2f((unsigned short)(v.x & 0xffff));
            acc[1] += w * b2f((unsigned short)(v.x >> 16));
            acc[2] += w * b2f((unsigned short)(v.y & 0xffff));
            acc[3] += w * b2f((unsigned short)(v.y >> 16));
            acc[4] += w * b2f((unsigned short)(v.z & 0xffff));
            acc[5] += w * b2f((unsigned short)(v.z >> 16));
            acc[6] += w * b2f((unsigned short)(v.w & 0xffff));
            acc[7] += w * b2f((unsigned short)(v.w >> 16));
        }
    }
    #pragma unroll
    for (int j = 0; j < 8; ++j) {
        acc[j] += __shfl_xor(acc[j], 8);
        acc[j] += __shfl_xor(acc[j], 16);
        acc[j] += __shfl_xor(acc[j], 32);
    }
    if (ln < 8) {
        float4 v0, v1;
        v0.x = acc[0]; v0.y = acc[1]; v0.z = acc[2]; v0.w = acc[3];
        v1.x = acc[4]; v1.y = acc[5]; v1.z = acc[6]; v1.w = acc[7];
        *reinterpret_cast<float4*>(&sOutp[wv][ln * 8])     = v0;
        *reinterpret_cast<float4*>(&sOutp[wv][ln * 8 + 4]) = v1;
    }
    __syncthreads();
    if (tid < H) {
        float o = (sOutp[0][tid] + sOutp[1][tid]) + (sOutp[2][tid] + sOutp[3][tid]);
        out[(size_t)b * H + tid] = o * inv;
    }
}

extern "C" void kernel_launch(void* const* d_in, const int* in_sizes, int n_in,
                              void* d_out, int out_size, void* d_ws, size_t ws_size,
                              hipStream_t stream) {
    const float* query       = (const float*)d_in[0];
    const float* keys        = (const float*)d_in[1];
    const int*   keys_length = (const int*)  d_in[2];
    const float* W1          = (const float*)d_in[3];
    const float* b1          = (const float*)d_in[4];
    const float* W2          = (const float*)d_in[5];
    const float* b2          = (const float*)d_in[6];
    const float* Wfc         = (const float*)d_in[7];
    const float* bfc         = (const float*)d_in[8];
    float* out = (float*)d_out;
    float* ws  = (float*)d_ws;

    prep_kernel<<<640, 256, 0, stream>>>(W1, W2, b1, query, ws);
    score_kernel<<<BT / 64, 256, 0, stream>>>(query, keys, b2, Wfc, bfc, ws);
    attn_out_kernel<<<BB, 256, 0, stream>>>(keys_length, ws, out);
}